// Round 1
// baseline (657.182 us; speedup 1.0000x reference)
//
#include <hip/hip_runtime.h>
#include <hip/hip_bf16.h>
#include <stdint.h>

// Problem constants (fixed by setup_inputs)
#define BB 4
#define TT 4096
#define CC 2048
#define HH 16
#define DD 128
#define MM (BB*TT)   // 16384
#define KK CC        // 2048
#define NNx CC       // 2048

#define NCH 16
#define CHL (TT/NCH) // 256

typedef unsigned short u16;
typedef unsigned int   u32;
typedef __bf16 bf16x8 __attribute__((ext_vector_type(8)));
typedef float  f32x4  __attribute__((ext_vector_type(4)));

__device__ __forceinline__ float bf2f(u32 lo) {
  union { u32 u; float f; } z; z.u = lo << 16; return z.f;
}
__device__ __forceinline__ u16 f2bf(float f) {
  union { float f; u32 u; } z; z.f = f;
  u32 u = z.u;
  return (u16)((u + 0x7FFFu + ((u >> 16) & 1u)) >> 16); // RNE
}

// ---------------- f32 -> bf16 convert (vectorized, 8 elem/thread) ----------
__global__ void cvt_f32_bf16(const float* __restrict__ in, u16* __restrict__ out, long n) {
  long i = ((long)blockIdx.x * blockDim.x + threadIdx.x) * 8;
  if (i >= n) return;
  float4 v0 = *(const float4*)(in + i);
  float4 v1 = *(const float4*)(in + i + 4);
  uint4 o;
  o.x = (u32)f2bf(v0.x) | ((u32)f2bf(v0.y) << 16);
  o.y = (u32)f2bf(v0.z) | ((u32)f2bf(v0.w) << 16);
  o.z = (u32)f2bf(v1.x) | ((u32)f2bf(v1.y) << 16);
  o.w = (u32)f2bf(v1.z) | ((u32)f2bf(v1.w) << 16);
  *(uint4*)(out + i) = o;
}

// ---------------- GEMM: C = A(M,K) * B(N,K)^T, bf16 in, f32 or bf16 out ----
// m97 structure: 128x128 tile, BK=32, 4 waves (2x2), 16x16x32 bf16 MFMA,
// double-buffered LDS staged via global_load_lds width=16.
__device__ __forceinline__ void gload16(const void* g, void* l) {
  __builtin_amdgcn_global_load_lds(
      (__attribute__((address_space(1))) void*)g,
      (__attribute__((address_space(3))) void*)l, 16, 0, 0);
}

template<int OUTF32>
__global__ __launch_bounds__(256)
void gemm_bt(const u16* __restrict__ A, const u16* __restrict__ Bm,
             float* __restrict__ Cf, u16* __restrict__ Cb)
{
  constexpr int N = NNx, K = KK;
  constexpr int NK = K / 32;
  __shared__ u16 As[2][128*32];
  __shared__ u16 Bs[2][128*32];
  const int tid  = threadIdx.x;
  const int wid  = tid >> 6;
  const int lane = tid & 63;
  const int m0 = blockIdx.y * 128;
  const int n0 = blockIdx.x * 128;

  // staging: 512 16B-chunks per matrix per K-step; chunk c -> row c>>2, q=c&3
  const int c0 = tid, c1 = tid + 256;
  const u16* gA0 = A  + (size_t)(m0 + (c0>>2))*K + (c0&3)*8;
  const u16* gA1 = A  + (size_t)(m0 + (c1>>2))*K + (c1&3)*8;
  const u16* gB0 = Bm + (size_t)(n0 + (c0>>2))*K + (c0&3)*8;
  const u16* gB1 = Bm + (size_t)(n0 + (c1>>2))*K + (c1&3)*8;
  // wave-uniform LDS bases (ushort units); HW adds lane*16B
  u16* lA0 = &As[0][wid*512];
  u16* lA1 = &As[0][2048 + wid*512];
  u16* lB0 = &Bs[0][wid*512];
  u16* lB1 = &Bs[0][2048 + wid*512];

  auto stage = [&](int buf, int kt) {
    const int ko = kt * 32;
    const int bo = buf * 4096;
    gload16(gA0 + ko, lA0 + bo);
    gload16(gA1 + ko, lA1 + bo);
    gload16(gB0 + ko, lB0 + bo);
    gload16(gB1 + ko, lB1 + bo);
  };

  const int wm = (wid >> 1) * 64, wn = (wid & 1) * 64;
  const int fr = lane & 15, kg = lane >> 4;
  int aoff[4], boff[4];
  #pragma unroll
  for (int f = 0; f < 4; ++f) {
    aoff[f] = (wm + f*16 + fr)*32 + kg*8;
    boff[f] = (wn + f*16 + fr)*32 + kg*8;
  }

  f32x4 acc[4][4];
  #pragma unroll
  for (int i = 0; i < 4; ++i)
    #pragma unroll
    for (int j = 0; j < 4; ++j) acc[i][j] = (f32x4){0.f,0.f,0.f,0.f};

  stage(0, 0);
  int buf = 0;
  for (int kt = 0; kt < NK; ++kt) {
    __syncthreads();                       // drains vmcnt -> staged tile ready
    if (kt + 1 < NK) stage(buf ^ 1, kt + 1);
    bf16x8 av[4], bv[4];
    #pragma unroll
    for (int f = 0; f < 4; ++f) av[f] = *(const bf16x8*)&As[buf][aoff[f]];
    #pragma unroll
    for (int f = 0; f < 4; ++f) bv[f] = *(const bf16x8*)&Bs[buf][boff[f]];
    #pragma unroll
    for (int i = 0; i < 4; ++i)
      #pragma unroll
      for (int j = 0; j < 4; ++j)
        acc[i][j] = __builtin_amdgcn_mfma_f32_16x16x32_bf16(av[i], bv[j], acc[i][j], 0, 0, 0);
    buf ^= 1;
  }

  // C/D layout: col = lane&15, row = (lane>>4)*4 + reg   [m89/m91]
  const int row0 = m0 + wm + kg*4;
  const int col0 = n0 + wn + fr;
  #pragma unroll
  for (int i = 0; i < 4; ++i)
    #pragma unroll
    for (int j = 0; j < 4; ++j)
      #pragma unroll
      for (int r = 0; r < 4; ++r) {
        const int row = row0 + i*16 + r;
        const int col = col0 + j*16;
        if (OUTF32) Cf[(size_t)row*N + col] = acc[i][j][r];
        else        Cb[(size_t)row*N + col] = f2bf(acc[i][j][r]);
      }
}

// ---------------- Scan stage 1: tmp(b,h,t) = temp[h]*(sum_d wsq/cumsum + D*db)
// chunked scan: partial sums -> exclusive scan -> chunk-local scan + D-reduce
__global__ __launch_bounds__(64)
void scan1_partial(const u16* __restrict__ w, float* __restrict__ S)
{
  const int ch = blockIdx.x, h = blockIdx.y, b = blockIdx.z;
  const int l = threadIdx.x;
  const u16* base = w + (size_t)b*TT*CC + (size_t)(ch*CHL)*CC + h*DD + 2*l;
  float s0 = 0.f, s1 = 0.f;
  #pragma unroll 8
  for (int t = 0; t < CHL; ++t) {
    u32 v = *(const u32*)(base + (size_t)t*CC);
    float a = bf2f(v & 0xffffu), c = bf2f(v >> 16);
    s0 += a*a; s1 += c*c;
  }
  float* Sp = S + ((size_t)((b*HH + h)*DD + 2*l))*NCH + ch;
  Sp[0] = s0; Sp[NCH] = s1;
}

__global__ void excl_scan(float* __restrict__ p, int nchan)
{
  int c = blockIdx.x * blockDim.x + threadIdx.x;
  if (c >= nchan) return;
  float* q = p + (size_t)c * NCH;
  float run = 0.f;
  #pragma unroll
  for (int i = 0; i < NCH; ++i) { float v = q[i]; q[i] = run; run += v; }
}

__global__ __launch_bounds__(64)
void scan1_main(const u16* __restrict__ w, const float* __restrict__ S,
                const float* __restrict__ temp, const float* __restrict__ dbias,
                float* __restrict__ tmpo)
{
  const int ch = blockIdx.x, h = blockIdx.y, b = blockIdx.z;
  const int l = threadIdx.x;
  const int t0 = ch * CHL;
  const u16* base = w + (size_t)b*TT*CC + (size_t)t0*CC + h*DD + 2*l;
  const float* Sp = S + ((size_t)((b*HH + h)*DD + 2*l))*NCH + ch;
  float c0 = Sp[0], c1 = Sp[NCH];
  const float th = temp[h];
  float* to = tmpo + (size_t)(b*HH + h)*TT + t0;
  const float* db = dbias + (size_t)h*TT + t0;
  #pragma unroll 4
  for (int t = 0; t < CHL; ++t) {
    u32 v = *(const u32*)(base + (size_t)t*CC);
    float a = bf2f(v & 0xffffu), c = bf2f(v >> 16);
    float a2 = a*a, c2 = c*c;
    c0 += a2; c1 += c2;
    float val = a2 / fmaxf(c0, 1e-12f) + c2 / fmaxf(c1, 1e-12f);
    #pragma unroll
    for (int o = 32; o; o >>= 1) val += __shfl_xor(val, o, 64);
    if (l == 0) to[t] = th * (val + (float)DD * db[t]);
  }
}

// ---------------- softmax over heads at each (b,t) -------------------------
__global__ void softmax_heads(const float* __restrict__ tmpo, float* __restrict__ Pi)
{
  const int i = blockIdx.x * blockDim.x + threadIdx.x;  // over B*T
  if (i >= BB*TT) return;
  const int b = i / TT, t = i - b*TT;
  const float* tp = tmpo + (size_t)b*HH*TT + t;
  float v[HH];
  float m = -1e30f;
  #pragma unroll
  for (int h = 0; h < HH; ++h) { v[h] = tp[(size_t)h*TT]; m = fmaxf(m, v[h]); }
  float s = 0.f;
  #pragma unroll
  for (int h = 0; h < HH; ++h) { v[h] = expf(v[h] - m); s += v[h]; }
  float inv = 1.f / s;
  float* pp = Pi + (size_t)b*HH*TT + t;
  #pragma unroll
  for (int h = 0; h < HH; ++h) pp[(size_t)h*TT] = v[h] * inv;
}

// ---------------- Scan stage 2: dots/attn/y, writes y_mid bf16 (B,T,C) -----
__global__ __launch_bounds__(64)
void scan2_partial(const u16* __restrict__ w, const float* __restrict__ Pi,
                   float* __restrict__ S2, float* __restrict__ SP)
{
  const int ch = blockIdx.x, h = blockIdx.y, b = blockIdx.z;
  const int l = threadIdx.x;
  const int t0 = ch * CHL;
  const u16* base = w + (size_t)b*TT*CC + (size_t)t0*CC + h*DD + 2*l;
  const float* pp = Pi + (size_t)(b*HH + h)*TT + t0;
  float s0 = 0.f, s1 = 0.f, sp = 0.f;
  #pragma unroll 4
  for (int t = 0; t < CHL; ++t) {
    u32 v = *(const u32*)(base + (size_t)t*CC);
    float a = bf2f(v & 0xffffu), c = bf2f(v >> 16);
    float pi = pp[t];
    s0 += a*a*pi; s1 += c*c*pi; sp += pi;
  }
  float* Sq = S2 + ((size_t)((b*HH + h)*DD + 2*l))*NCH + ch;
  Sq[0] = s0; Sq[NCH] = s1;
  if (l == 0) SP[(size_t)(b*HH + h)*NCH + ch] = sp;
}

__global__ __launch_bounds__(64)
void scan2_main(const u16* __restrict__ w, const float* __restrict__ Pi,
                const float* __restrict__ S2, const float* __restrict__ SP,
                u16* __restrict__ ymid)
{
  const int ch = blockIdx.x, h = blockIdx.y, b = blockIdx.z;
  const int l = threadIdx.x;
  const int t0 = ch * CHL;
  const u16* base = w + (size_t)b*TT*CC + (size_t)t0*CC + h*DD + 2*l;
  u16* yo = ymid + (size_t)b*TT*CC + (size_t)t0*CC + h*DD + 2*l;
  const float* pp = Pi + (size_t)(b*HH + h)*TT + t0;
  const float* Sq = S2 + ((size_t)((b*HH + h)*DD + 2*l))*NCH + ch;
  float c0 = Sq[0], c1 = Sq[NCH];
  float cp = SP[(size_t)(b*HH + h)*NCH + ch];
  #pragma unroll 4
  for (int t = 0; t < CHL; ++t) {
    u32 v = *(const u32*)(base + (size_t)t*CC);
    float a = bf2f(v & 0xffffu), c = bf2f(v >> 16);
    float pi = pp[t];
    cp += pi;
    c0 += a*a*pi; c1 += c*c*pi;
    float invp = 1.f / (cp + 1e-8f);
    float d0 = c0 * invp, d1 = c1 * invp;
    float y0 = -(a * pi) / (1.f + d0);
    float y1 = -(c * pi) / (1.f + d1);
    u32 o = (u32)f2bf(y0) | ((u32)f2bf(y1) << 16);
    *(u32*)(yo + (size_t)t*CC) = o;
  }
}

// ---------------- launch ----------------------------------------------------
extern "C" void kernel_launch(void* const* d_in, const int* in_sizes, int n_in,
                              void* d_out, int out_size, void* d_ws, size_t ws_size,
                              hipStream_t stream) {
  const float* x     = (const float*)d_in[0];
  const float* Wa    = (const float*)d_in[1];
  const float* Wp    = (const float*)d_in[2];
  const float* temp  = (const float*)d_in[3];
  const float* dbias = (const float*)d_in[4];
  float* out = (float*)d_out;

  char* ws = (char*)d_ws;
  // workspace layout (total ~147 MiB)
  u16*  xb   = (u16*)(ws);                      // 67,108,864 B
  u16*  Wab  = (u16*)(ws + 67108864);           //  8,388,608
  u16*  Wpb  = (u16*)(ws + 75497472);           //  8,388,608
  u16*  wbuf = (u16*)(ws + 83886080);           // 67,108,864
  float* tmpb = (float*)(ws + 150994944);       //  1,048,576
  float* Pib  = (float*)(ws + 152043520);       //  1,048,576
  float* S1   = (float*)(ws + 153092096);       //    524,288
  float* S2   = (float*)(ws + 153616384);       //    524,288
  float* SP   = (float*)(ws + 154140672);       //      4,096
  u16*  ymid = xb;  // xb dead after GEMM1 -> reuse

  // 1) convert inputs to bf16
  cvt_f32_bf16<<<(MM*(long)KK)/8/256, 256, 0, stream>>>(x,  xb,  (long)MM*KK);
  cvt_f32_bf16<<<((long)CC*CC)/8/256, 256, 0, stream>>>(Wa, Wab, (long)CC*CC);
  cvt_f32_bf16<<<((long)CC*CC)/8/256, 256, 0, stream>>>(Wp, Wpb, (long)CC*CC);

  // 2) w = x @ Wa^T  (bf16 out)
  dim3 gg(NNx/128, MM/128);
  gemm_bt<0><<<gg, 256, 0, stream>>>(xb, Wab, nullptr, wbuf);

  // 3) first causal scan -> tmp
  dim3 gs(NCH, HH, BB);
  scan1_partial<<<gs, 64, 0, stream>>>(wbuf, S1);
  excl_scan<<<(BB*HH*DD + 255)/256, 256, 0, stream>>>(S1, BB*HH*DD);
  scan1_main<<<gs, 64, 0, stream>>>(wbuf, S1, temp, dbias, tmpb);

  // 4) softmax over heads
  softmax_heads<<<(BB*TT)/256, 256, 0, stream>>>(tmpb, Pib);

  // 5) second causal scan -> y_mid (bf16, (B,T,C))
  scan2_partial<<<gs, 64, 0, stream>>>(wbuf, Pib, S2, SP);
  excl_scan<<<(BB*HH*DD + 255)/256, 256, 0, stream>>>(S2, BB*HH*DD);
  excl_scan<<<1, 64, 0, stream>>>(SP, BB*HH);
  scan2_main<<<gs, 64, 0, stream>>>(wbuf, Pib, S2, SP, ymid);

  // 6) out = y_mid @ Wp^T (f32 out)
  gemm_bt<1><<<gg, 256, 0, stream>>>(ymid, Wpb, out, nullptr);
}

// Round 2
// 581.311 us; speedup vs baseline: 1.1305x; 1.1305x over previous
//
#include <hip/hip_runtime.h>
#include <hip/hip_bf16.h>
#include <stdint.h>

// Problem constants (fixed by setup_inputs)
#define BB 4
#define TT 4096
#define CC 2048
#define HH 16
#define DD 128
#define MM (BB*TT)   // 16384
#define KK CC        // 2048
#define NNx CC       // 2048
#define NTP 16       // K / 128 (tile-pairs of 2x64)

#define NCH 16
#define CHL (TT/NCH) // 256

typedef unsigned short u16;
typedef unsigned int   u32;
typedef __bf16 bf16x8 __attribute__((ext_vector_type(8)));
typedef float  f32x4  __attribute__((ext_vector_type(4)));

__device__ __forceinline__ float bf2f(u32 lo) {
  union { u32 u; float f; } z; z.u = lo << 16; return z.f;
}
__device__ __forceinline__ u16 f2bf(float f) {
  union { float f; u32 u; } z; z.f = f;
  u32 u = z.u;
  return (u16)((u + 0x7FFFu + ((u >> 16) & 1u)) >> 16); // RNE
}

// ---------------- f32 -> bf16 convert (vectorized, 8 elem/thread) ----------
__global__ void cvt_f32_bf16(const float* __restrict__ in, u16* __restrict__ out, long n) {
  long i = ((long)blockIdx.x * blockDim.x + threadIdx.x) * 8;
  if (i >= n) return;
  float4 v0 = *(const float4*)(in + i);
  float4 v1 = *(const float4*)(in + i + 4);
  uint4 o;
  o.x = (u32)f2bf(v0.x) | ((u32)f2bf(v0.y) << 16);
  o.y = (u32)f2bf(v0.z) | ((u32)f2bf(v0.w) << 16);
  o.z = (u32)f2bf(v1.x) | ((u32)f2bf(v1.y) << 16);
  o.w = (u32)f2bf(v1.z) | ((u32)f2bf(v1.w) << 16);
  *(uint4*)(out + i) = o;
}

__device__ __forceinline__ void gload16(const void* g, void* l) {
  __builtin_amdgcn_global_load_lds(
      (__attribute__((address_space(1))) void*)g,
      (__attribute__((address_space(3))) void*)l, 16, 0, 0);
}

// ---------------- GEMM: C = A(M,K) * B(N,K)^T, 256x256 tile, 8-phase -------
// 8 waves (2M x 4N), K-tiles of 64 split in K-halves of 32.
// LDS: ring of 4 slots per matrix, slot = (2*tile + khalf) & 3 (iter-invariant):
//   slot0=(e,k0) slot1=(e,k1) slot2=(o,k0) slot3=(o,k1), e=2i, o=2i+1.
// Per phase: 4/8 ds_read_b128 + one half-stage (2 global_load_lds w=16) +
// barrier + 16 MFMA (setprio-wrapped) + barrier. Counted vmcnt(4) at P4/P8.
// LDS swizzle: 16B chunk' = chunk ^ ((row>>1)&3), applied on the global
// source (stage) and the ds_read offset (both-sides involution, rule #21).
template<int OUTF32>
__global__ __launch_bounds__(512, 2)
void gemm256(const u16* __restrict__ A, const u16* __restrict__ Bm,
             float* __restrict__ Cf, u16* __restrict__ Cb)
{
  __shared__ u16 As[4][8192];   // 4 x 16KB
  __shared__ u16 Bs[4][8192];   // 4 x 16KB   (total 128 KB)
  const int tid  = threadIdx.x;
  const int wid  = tid >> 6;
  const int lane = tid & 63;
  const int wm = wid >> 2, wn = wid & 3;     // 2 x 4 wave grid
  const int fr = lane & 15, kg = lane >> 4;
  const int m0 = blockIdx.y * 256;
  const int n0 = blockIdx.x * 256;           // nb = bid%8 -> per-XCD B panel

  // staging: thread tid stages chunk g = j*512+tid -> (row=g>>2, chunk'=tid&3)
  const int srow = tid >> 2;                       // 0..127 (j adds 128)
  const int sc   = (tid & 3) ^ ((srow >> 1) & 3);  // logical source chunk
  const u16* gA0 = A  + (size_t)(m0 + srow) * KK + sc * 8;
  const u16* gA1 = gA0 + (size_t)128 * KK;
  const u16* gB0 = Bm + (size_t)(n0 + srow) * KK + sc * 8;
  const u16* gB1 = gB0 + (size_t)128 * KK;
  const int ldst0 = wid * 512;          // u16 units; lane adds 8 (16B) in HW
  const int ldst1 = 4096 + wid * 512;

  // ds_read swizzle: row = (mult of 16)+fr  ->  (row>>1)&3 == (fr>>1)&3
  const int cs    = kg ^ ((fr >> 1) & 3);
  const int abase = (wm * 128 + fr) * 32 + cs * 8;
  const int bbase = (wn * 64  + fr) * 32 + cs * 8;

  f32x4 acc[8][4];
  #pragma unroll
  for (int i = 0; i < 8; ++i)
    #pragma unroll
    for (int j = 0; j < 4; ++j) acc[i][j] = (f32x4){0.f,0.f,0.f,0.f};

  auto stA = [&](int slot, int ko) {
    gload16(gA0 + ko, &As[slot][ldst0]);
    gload16(gA1 + ko, &As[slot][ldst1]);
  };
  auto stB = [&](int slot, int ko) {
    gload16(gB0 + ko, &Bs[slot][ldst0]);
    gload16(gB1 + ko, &Bs[slot][ldst1]);
  };

  // prologue: tile0 k0,k1 ; tile1 k0. vmcnt(2) -> slots 0,1 landed.
  stA(0, 0);  stB(0, 0);
  stA(1, 32); stB(1, 32);
  stA(2, 64); stB(2, 64);
  asm volatile("s_waitcnt vmcnt(2)" ::: "memory");
  __builtin_amdgcn_s_barrier();

  bf16x8 av[4], bv[4];

#define PH(CSLOT, MH, LOADB, STMT, DOWAIT) do {                               \
    _Pragma("unroll")                                                         \
    for (int f = 0; f < 4; ++f)                                               \
      av[f] = *(const bf16x8*)&As[CSLOT][abase + ((MH)*64 + f*16)*32];        \
    if (LOADB) {                                                              \
      _Pragma("unroll")                                                       \
      for (int f = 0; f < 4; ++f)                                             \
        bv[f] = *(const bf16x8*)&Bs[CSLOT][bbase + f*16*32];                  \
    }                                                                         \
    STMT;                                                                     \
    if (DOWAIT) asm volatile("s_waitcnt vmcnt(4)" ::: "memory");              \
    __builtin_amdgcn_s_barrier();                                             \
    __builtin_amdgcn_s_setprio(1);                                            \
    _Pragma("unroll")                                                         \
    for (int f = 0; f < 4; ++f)                                               \
      _Pragma("unroll")                                                       \
      for (int n = 0; n < 4; ++n)                                             \
        acc[(MH)*4+f][n] = __builtin_amdgcn_mfma_f32_16x16x32_bf16(          \
            av[f], bv[n], acc[(MH)*4+f][n], 0, 0, 0);                         \
    __builtin_amdgcn_s_setprio(0);                                            \
    __builtin_amdgcn_s_barrier();                                             \
  } while (0)

  for (int it = 0; it < NTP; ++it) {
    const int kb = it * 128;
    const bool nx = (it + 1 < NTP);
    PH(0, 0, 1, stA(3, kb + 96), 0);           // P1: e,k0,mh0 | stage o.k1 A
    PH(0, 1, 0, stB(3, kb + 96), 0);           // P2: e,k0,mh1 | stage o.k1 B
    PH(1, 0, 1, if (nx) stA(0, kb + 128), 0);  // P3: e,k1,mh0 | stage e'.k0 A
    PH(1, 1, 0, if (nx) stB(0, kb + 128), 1);  // P4: e,k1,mh1 | stage e'.k0 B | vmcnt(4)
    PH(2, 0, 1, if (nx) stA(1, kb + 160), 0);  // P5: o,k0,mh0 | stage e'.k1 A
    PH(2, 1, 0, if (nx) stB(1, kb + 160), 0);  // P6: o,k0,mh1 | stage e'.k1 B
    PH(3, 0, 1, if (nx) stA(2, kb + 192), 0);  // P7: o,k1,mh0 | stage o'.k0 A
    PH(3, 1, 0, if (nx) stB(2, kb + 192), 1);  // P8: o,k1,mh1 | stage o'.k0 B | vmcnt(4)
  }
#undef PH

  // C/D layout: col = lane&15, row = (lane>>4)*4 + reg   [m89/m91]
  const int row0 = m0 + wm * 128 + kg * 4;
  const int col0 = n0 + wn * 64 + fr;
  #pragma unroll
  for (int mf = 0; mf < 8; ++mf)
    #pragma unroll
    for (int nf = 0; nf < 4; ++nf)
      #pragma unroll
      for (int r = 0; r < 4; ++r) {
        const int row = row0 + mf * 16 + r;
        const int col = col0 + nf * 16;
        if (OUTF32) Cf[(size_t)row * NNx + col] = acc[mf][nf][r];
        else        Cb[(size_t)row * NNx + col] = f2bf(acc[mf][nf][r]);
      }
}

// ---------------- Scan stage 1 ---------------------------------------------
__global__ __launch_bounds__(64)
void scan1_partial(const u16* __restrict__ w, float* __restrict__ S)
{
  const int ch = blockIdx.x, h = blockIdx.y, b = blockIdx.z;
  const int l = threadIdx.x;
  const u16* base = w + (size_t)b*TT*CC + (size_t)(ch*CHL)*CC + h*DD + 2*l;
  float s0 = 0.f, s1 = 0.f;
  #pragma unroll 8
  for (int t = 0; t < CHL; ++t) {
    u32 v = *(const u32*)(base + (size_t)t*CC);
    float a = bf2f(v & 0xffffu), c = bf2f(v >> 16);
    s0 += a*a; s1 += c*c;
  }
  float* Sp = S + ((size_t)((b*HH + h)*DD + 2*l))*NCH + ch;
  Sp[0] = s0; Sp[NCH] = s1;
}

__global__ void excl_scan(float* __restrict__ p, int nchan)
{
  int c = blockIdx.x * blockDim.x + threadIdx.x;
  if (c >= nchan) return;
  float* q = p + (size_t)c * NCH;
  float run = 0.f;
  #pragma unroll
  for (int i = 0; i < NCH; ++i) { float v = q[i]; q[i] = run; run += v; }
}

__global__ __launch_bounds__(64)
void scan1_main(const u16* __restrict__ w, const float* __restrict__ S,
                const float* __restrict__ temp, const float* __restrict__ dbias,
                float* __restrict__ tmpo)
{
  const int ch = blockIdx.x, h = blockIdx.y, b = blockIdx.z;
  const int l = threadIdx.x;
  const int t0 = ch * CHL;
  const u16* base = w + (size_t)b*TT*CC + (size_t)t0*CC + h*DD + 2*l;
  const float* Sp = S + ((size_t)((b*HH + h)*DD + 2*l))*NCH + ch;
  float c0 = Sp[0], c1 = Sp[NCH];
  const float th = temp[h];
  float* to = tmpo + (size_t)(b*HH + h)*TT + t0;
  const float* db = dbias + (size_t)h*TT + t0;
  #pragma unroll 4
  for (int t = 0; t < CHL; ++t) {
    u32 v = *(const u32*)(base + (size_t)t*CC);
    float a = bf2f(v & 0xffffu), c = bf2f(v >> 16);
    float a2 = a*a, c2 = c*c;
    c0 += a2; c1 += c2;
    float val = a2 / fmaxf(c0, 1e-12f) + c2 / fmaxf(c1, 1e-12f);
    #pragma unroll
    for (int o = 32; o; o >>= 1) val += __shfl_xor(val, o, 64);
    if (l == 0) to[t] = th * (val + (float)DD * db[t]);
  }
}

// ---------------- softmax over heads at each (b,t) -------------------------
__global__ void softmax_heads(const float* __restrict__ tmpo, float* __restrict__ Pi)
{
  const int i = blockIdx.x * blockDim.x + threadIdx.x;  // over B*T
  if (i >= BB*TT) return;
  const int b = i / TT, t = i - b*TT;
  const float* tp = tmpo + (size_t)b*HH*TT + t;
  float v[HH];
  float m = -1e30f;
  #pragma unroll
  for (int h = 0; h < HH; ++h) { v[h] = tp[(size_t)h*TT]; m = fmaxf(m, v[h]); }
  float s = 0.f;
  #pragma unroll
  for (int h = 0; h < HH; ++h) { v[h] = expf(v[h] - m); s += v[h]; }
  float inv = 1.f / s;
  float* pp = Pi + (size_t)b*HH*TT + t;
  #pragma unroll
  for (int h = 0; h < HH; ++h) pp[(size_t)h*TT] = v[h] * inv;
}

// ---------------- Scan stage 2 ---------------------------------------------
__global__ __launch_bounds__(64)
void scan2_partial(const u16* __restrict__ w, const float* __restrict__ Pi,
                   float* __restrict__ S2, float* __restrict__ SP)
{
  const int ch = blockIdx.x, h = blockIdx.y, b = blockIdx.z;
  const int l = threadIdx.x;
  const int t0 = ch * CHL;
  const u16* base = w + (size_t)b*TT*CC + (size_t)t0*CC + h*DD + 2*l;
  const float* pp = Pi + (size_t)(b*HH + h)*TT + t0;
  float s0 = 0.f, s1 = 0.f, sp = 0.f;
  #pragma unroll 4
  for (int t = 0; t < CHL; ++t) {
    u32 v = *(const u32*)(base + (size_t)t*CC);
    float a = bf2f(v & 0xffffu), c = bf2f(v >> 16);
    float pi = pp[t];
    s0 += a*a*pi; s1 += c*c*pi; sp += pi;
  }
  float* Sq = S2 + ((size_t)((b*HH + h)*DD + 2*l))*NCH + ch;
  Sq[0] = s0; Sq[NCH] = s1;
  if (l == 0) SP[(size_t)(b*HH + h)*NCH + ch] = sp;
}

__global__ __launch_bounds__(64)
void scan2_main(const u16* __restrict__ w, const float* __restrict__ Pi,
                const float* __restrict__ S2, const float* __restrict__ SP,
                u16* __restrict__ ymid)
{
  const int ch = blockIdx.x, h = blockIdx.y, b = blockIdx.z;
  const int l = threadIdx.x;
  const int t0 = ch * CHL;
  const u16* base = w + (size_t)b*TT*CC + (size_t)t0*CC + h*DD + 2*l;
  u16* yo = ymid + (size_t)b*TT*CC + (size_t)t0*CC + h*DD + 2*l;
  const float* pp = Pi + (size_t)(b*HH + h)*TT + t0;
  const float* Sq = S2 + ((size_t)((b*HH + h)*DD + 2*l))*NCH + ch;
  float c0 = Sq[0], c1 = Sq[NCH];
  float cp = SP[(size_t)(b*HH + h)*NCH + ch];
  #pragma unroll 4
  for (int t = 0; t < CHL; ++t) {
    u32 v = *(const u32*)(base + (size_t)t*CC);
    float a = bf2f(v & 0xffffu), c = bf2f(v >> 16);
    float pi = pp[t];
    cp += pi;
    c0 += a*a*pi; c1 += c*c*pi;
    float invp = 1.f / (cp + 1e-8f);
    float d0 = c0 * invp, d1 = c1 * invp;
    float y0 = -(a * pi) / (1.f + d0);
    float y1 = -(c * pi) / (1.f + d1);
    u32 o = (u32)f2bf(y0) | ((u32)f2bf(y1) << 16);
    *(u32*)(yo + (size_t)t*CC) = o;
  }
}

// ---------------- launch ----------------------------------------------------
extern "C" void kernel_launch(void* const* d_in, const int* in_sizes, int n_in,
                              void* d_out, int out_size, void* d_ws, size_t ws_size,
                              hipStream_t stream) {
  const float* x     = (const float*)d_in[0];
  const float* Wa    = (const float*)d_in[1];
  const float* Wp    = (const float*)d_in[2];
  const float* temp  = (const float*)d_in[3];
  const float* dbias = (const float*)d_in[4];
  float* out = (float*)d_out;

  char* ws = (char*)d_ws;
  u16*  xb   = (u16*)(ws);                      // 67,108,864 B
  u16*  Wab  = (u16*)(ws + 67108864);           //  8,388,608
  u16*  Wpb  = (u16*)(ws + 75497472);           //  8,388,608
  u16*  wbuf = (u16*)(ws + 83886080);           // 67,108,864
  float* tmpb = (float*)(ws + 150994944);       //  1,048,576
  float* Pib  = (float*)(ws + 152043520);       //  1,048,576
  float* S1   = (float*)(ws + 153092096);       //    524,288
  float* S2   = (float*)(ws + 153616384);       //    524,288
  float* SP   = (float*)(ws + 154140672);       //      4,096
  u16*  ymid = xb;  // xb dead after GEMM1 -> reuse

  // 1) convert inputs to bf16
  cvt_f32_bf16<<<(MM*(long)KK)/8/256, 256, 0, stream>>>(x,  xb,  (long)MM*KK);
  cvt_f32_bf16<<<((long)CC*CC)/8/256, 256, 0, stream>>>(Wa, Wab, (long)CC*CC);
  cvt_f32_bf16<<<((long)CC*CC)/8/256, 256, 0, stream>>>(Wp, Wpb, (long)CC*CC);

  // 2) w = x @ Wa^T  (bf16 out), 256^2 tiles: grid (N/256, M/256)
  dim3 gg(NNx/256, MM/256);
  gemm256<0><<<gg, 512, 0, stream>>>(xb, Wab, nullptr, wbuf);

  // 3) first causal scan -> tmp
  dim3 gs(NCH, HH, BB);
  scan1_partial<<<gs, 64, 0, stream>>>(wbuf, S1);
  excl_scan<<<(BB*HH*DD + 255)/256, 256, 0, stream>>>(S1, BB*HH*DD);
  scan1_main<<<gs, 64, 0, stream>>>(wbuf, S1, temp, dbias, tmpb);

  // 4) softmax over heads
  softmax_heads<<<(BB*TT)/256, 256, 0, stream>>>(tmpb, Pib);

  // 5) second causal scan -> y_mid (bf16, (B,T,C))
  scan2_partial<<<gs, 64, 0, stream>>>(wbuf, Pib, S2, SP);
  excl_scan<<<(BB*HH*DD + 255)/256, 256, 0, stream>>>(S2, BB*HH*DD);
  excl_scan<<<1, 64, 0, stream>>>(SP, BB*HH);
  scan2_main<<<gs, 64, 0, stream>>>(wbuf, Pib, S2, SP, ymid);

  // 6) out = y_mid @ Wp^T (f32 out)
  gemm256<1><<<gg, 512, 0, stream>>>(ymid, Wpb, out, nullptr);
}

// Round 3
// 422.716 us; speedup vs baseline: 1.5547x; 1.3752x over previous
//
#include <hip/hip_runtime.h>
#include <hip/hip_bf16.h>
#include <stdint.h>

// Problem constants (fixed by setup_inputs)
#define BB 4
#define TT 4096
#define CC 2048
#define HH 16
#define DD 128
#define MM (BB*TT)   // 16384
#define KK CC        // 2048
#define NNx CC       // 2048
#define NTP 16       // K / 128 (tile-pairs of 2x64)

#define NCH 128
#define CHL (TT/NCH) // 32

typedef unsigned short u16;
typedef unsigned int   u32;
typedef __bf16 bf16x8 __attribute__((ext_vector_type(8)));
typedef float  f32x4  __attribute__((ext_vector_type(4)));

__device__ __forceinline__ float bf2f(u32 lo) {
  union { u32 u; float f; } z; z.u = lo << 16; return z.f;
}
__device__ __forceinline__ u16 f2bf(float f) {
  union { float f; u32 u; } z; z.f = f;
  u32 u = z.u;
  return (u16)((u + 0x7FFFu + ((u >> 16) & 1u)) >> 16); // RNE
}
__device__ __forceinline__ void unpack8(uint4 v, float* a) {
  a[0]=bf2f(v.x&0xffffu); a[1]=bf2f(v.x>>16);
  a[2]=bf2f(v.y&0xffffu); a[3]=bf2f(v.y>>16);
  a[4]=bf2f(v.z&0xffffu); a[5]=bf2f(v.z>>16);
  a[6]=bf2f(v.w&0xffffu); a[7]=bf2f(v.w>>16);
}

// ---------------- f32 -> bf16 convert (vectorized, 8 elem/thread) ----------
__global__ void cvt_f32_bf16(const float* __restrict__ in, u16* __restrict__ out, long n) {
  long i = ((long)blockIdx.x * blockDim.x + threadIdx.x) * 8;
  if (i >= n) return;
  float4 v0 = *(const float4*)(in + i);
  float4 v1 = *(const float4*)(in + i + 4);
  uint4 o;
  o.x = (u32)f2bf(v0.x) | ((u32)f2bf(v0.y) << 16);
  o.y = (u32)f2bf(v0.z) | ((u32)f2bf(v0.w) << 16);
  o.z = (u32)f2bf(v1.x) | ((u32)f2bf(v1.y) << 16);
  o.w = (u32)f2bf(v1.z) | ((u32)f2bf(v1.w) << 16);
  *(uint4*)(out + i) = o;
}

__device__ __forceinline__ void gload16(const void* g, void* l) {
  __builtin_amdgcn_global_load_lds(
      (__attribute__((address_space(1))) void*)g,
      (__attribute__((address_space(3))) void*)l, 16, 0, 0);
}

// ---------------- GEMM: C = A(M,K) * B(N,K)^T, 256x256 tile, 8-phase -------
// (structure proven in round 2: swizzled LDS ring, counted vmcnt, setprio)
// EPI=1 additionally emits per-32-row-chunk column sums of (rounded bf16)^2
// into S1[ch][b*CC+col] — the scan1 partial pass, fused (unique writer,
// plain stores).
template<int OUTF32, int EPI>
__global__ __launch_bounds__(512, 2)
void gemm256(const u16* __restrict__ A, const u16* __restrict__ Bm,
             float* __restrict__ Cf, u16* __restrict__ Cb,
             float* __restrict__ S1)
{
  __shared__ u16 As[4][8192];   // 4 x 16KB
  __shared__ u16 Bs[4][8192];   // 4 x 16KB   (total 128 KB)
  const int tid  = threadIdx.x;
  const int wid  = tid >> 6;
  const int lane = tid & 63;
  const int wm = wid >> 2, wn = wid & 3;     // 2 x 4 wave grid
  const int fr = lane & 15, kg = lane >> 4;
  const int m0 = blockIdx.y * 256;
  const int n0 = blockIdx.x * 256;           // bid%8 -> per-XCD B panel

  const int srow = tid >> 2;                       // 0..127 (j adds 128)
  const int sc   = (tid & 3) ^ ((srow >> 1) & 3);  // pre-swizzled source chunk
  const u16* gA0 = A  + (size_t)(m0 + srow) * KK + sc * 8;
  const u16* gA1 = gA0 + (size_t)128 * KK;
  const u16* gB0 = Bm + (size_t)(n0 + srow) * KK + sc * 8;
  const u16* gB1 = gB0 + (size_t)128 * KK;
  const int ldst0 = wid * 512;
  const int ldst1 = 4096 + wid * 512;

  const int cs    = kg ^ ((fr >> 1) & 3);
  const int abase = (wm * 128 + fr) * 32 + cs * 8;
  const int bbase = (wn * 64  + fr) * 32 + cs * 8;

  f32x4 acc[8][4];
  #pragma unroll
  for (int i = 0; i < 8; ++i)
    #pragma unroll
    for (int j = 0; j < 4; ++j) acc[i][j] = (f32x4){0.f,0.f,0.f,0.f};

  auto stA = [&](int slot, int ko) {
    gload16(gA0 + ko, &As[slot][ldst0]);
    gload16(gA1 + ko, &As[slot][ldst1]);
  };
  auto stB = [&](int slot, int ko) {
    gload16(gB0 + ko, &Bs[slot][ldst0]);
    gload16(gB1 + ko, &Bs[slot][ldst1]);
  };

  stA(0, 0);  stB(0, 0);
  stA(1, 32); stB(1, 32);
  stA(2, 64); stB(2, 64);
  asm volatile("s_waitcnt vmcnt(2)" ::: "memory");
  __builtin_amdgcn_s_barrier();

  bf16x8 av[4], bv[4];

#define PH(CSLOT, MH, LOADB, STMT, DOWAIT) do {                               \
    _Pragma("unroll")                                                         \
    for (int f = 0; f < 4; ++f)                                               \
      av[f] = *(const bf16x8*)&As[CSLOT][abase + ((MH)*64 + f*16)*32];        \
    if (LOADB) {                                                              \
      _Pragma("unroll")                                                       \
      for (int f = 0; f < 4; ++f)                                             \
        bv[f] = *(const bf16x8*)&Bs[CSLOT][bbase + f*16*32];                  \
    }                                                                         \
    STMT;                                                                     \
    if (DOWAIT) asm volatile("s_waitcnt vmcnt(4)" ::: "memory");              \
    __builtin_amdgcn_s_barrier();                                             \
    __builtin_amdgcn_s_setprio(1);                                            \
    _Pragma("unroll")                                                         \
    for (int f = 0; f < 4; ++f)                                               \
      _Pragma("unroll")                                                       \
      for (int n = 0; n < 4; ++n)                                             \
        acc[(MH)*4+f][n] = __builtin_amdgcn_mfma_f32_16x16x32_bf16(          \
            av[f], bv[n], acc[(MH)*4+f][n], 0, 0, 0);                         \
    __builtin_amdgcn_s_setprio(0);                                            \
    __builtin_amdgcn_s_barrier();                                             \
  } while (0)

  for (int it = 0; it < NTP; ++it) {
    const int kb = it * 128;
    const bool nx = (it + 1 < NTP);
    PH(0, 0, 1, stA(3, kb + 96), 0);
    PH(0, 1, 0, stB(3, kb + 96), 0);
    PH(1, 0, 1, if (nx) stA(0, kb + 128), 0);
    PH(1, 1, 0, if (nx) stB(0, kb + 128), 1);
    PH(2, 0, 1, if (nx) stA(1, kb + 160), 0);
    PH(2, 1, 0, if (nx) stB(1, kb + 160), 0);
    PH(3, 0, 1, if (nx) stA(2, kb + 192), 0);
    PH(3, 1, 0, if (nx) stB(2, kb + 192), 1);
  }
#undef PH

  // C/D layout: col = lane&15, row = (lane>>4)*4 + reg   [m89/m91]
  const int row0 = m0 + wm * 128 + kg * 4;
  const int col0 = n0 + wn * 64 + fr;
  if (OUTF32) {
    #pragma unroll
    for (int mf = 0; mf < 8; ++mf)
      #pragma unroll
      for (int nf = 0; nf < 4; ++nf)
        #pragma unroll
        for (int r = 0; r < 4; ++r)
          Cf[(size_t)(row0 + mf*16 + r) * NNx + col0 + nf*16] = acc[mf][nf][r];
  } else {
    float csum[4][4];
    #pragma unroll
    for (int p = 0; p < 4; ++p)
      #pragma unroll
      for (int nf = 0; nf < 4; ++nf) csum[p][nf] = 0.f;
    #pragma unroll
    for (int mf = 0; mf < 8; ++mf)
      #pragma unroll
      for (int nf = 0; nf < 4; ++nf)
        #pragma unroll
        for (int r = 0; r < 4; ++r) {
          u16 hb = f2bf(acc[mf][nf][r]);
          Cb[(size_t)(row0 + mf*16 + r) * NNx + col0 + nf*16] = hb;
          if (EPI) { float av_ = bf2f(hb); csum[mf>>1][nf] += av_ * av_; }
        }
    if (EPI) {
      // reduce over kg (rows kg*4+r) and store per 32-row chunk
      const int b   = m0 >> 12;                 // m0 / TT
      const int ch0 = ((m0 & (TT-1)) >> 5) + wm * 4;
      #pragma unroll
      for (int p = 0; p < 4; ++p)
        #pragma unroll
        for (int nf = 0; nf < 4; ++nf) {
          float v = csum[p][nf];
          v += __shfl_xor(v, 16, 64);
          v += __shfl_xor(v, 32, 64);
          if (kg == 0)
            S1[(size_t)(ch0 + p) * (BB*CC) + b * CC + col0 + nf*16] = v;
        }
    }
  }
}

// ---------------- exclusive scan over chunk axis ---------------------------
// S layout: [NCH][BB*CC]; one thread per (b,c) column, coalesced.
__global__ void excl_big(float* __restrict__ p) {
  const int g = blockIdx.x * 256 + threadIdx.x;   // 0..8191
  float run = 0.f;
  for (int ch = 0; ch < NCH; ++ch) {
    float v = p[(size_t)ch * (BB*CC) + g];
    p[(size_t)ch * (BB*CC) + g] = run;
    run += v;
  }
}
__global__ void excl_sp(float* __restrict__ p) {
  const int g = threadIdx.x;                       // 0..63 (b*HH+h)
  float run = 0.f;
  for (int ch = 0; ch < NCH; ++ch) {
    float v = p[ch * (BB*HH) + g];
    p[ch * (BB*HH) + g] = run;
    run += v;
  }
}

// ---------------- Pass C: scan1_main + head softmax + scan2_partial --------
// block = (chunk, b); 256 threads cover all 2048 channels (8 per thread).
// S: in = excl-scanned scan1 offsets; out (in-place) = scan2 chunk partials.
__global__ __launch_bounds__(256)
void pass_c(const u16* __restrict__ w, float* __restrict__ S,
            float* __restrict__ SP, float* __restrict__ Pi,
            const float* __restrict__ temp, const float* __restrict__ dbias)
{
  __shared__ float sm[2][HH];
  const int ch = blockIdx.x, b = blockIdx.y;
  const int tid = threadIdx.x;
  const int h = tid >> 4;
  const int t0 = ch * CHL;
  const u16* wrow = w + ((size_t)b*TT + t0) * CC + tid*8;
  float* Srow = S + (size_t)ch * (BB*CC) + b * CC + tid*8;
  float c0[8], s2[8];
  #pragma unroll
  for (int j = 0; j < 8; ++j) { c0[j] = Srow[j]; s2[j] = 0.f; }
  const float th = temp[h];
  const float* db = dbias + (size_t)h * TT + t0;
  float sp = 0.f;
  uint4 v = *(const uint4*)wrow;
  for (int t = 0; t < CHL; ++t) {
    uint4 vn = v;
    if (t + 1 < CHL) vn = *(const uint4*)(wrow + (size_t)(t+1) * CC);
    float a2[8];
    { float a[8]; unpack8(v, a);
      #pragma unroll
      for (int j = 0; j < 8; ++j) a2[j] = a[j]*a[j]; }
    float val = 0.f;
    #pragma unroll
    for (int j = 0; j < 8; ++j) {
      c0[j] += a2[j];
      val += a2[j] * __builtin_amdgcn_rcpf(fmaxf(c0[j], 1e-12f));
    }
    val += __shfl_xor(val, 1, 64);
    val += __shfl_xor(val, 2, 64);
    val += __shfl_xor(val, 4, 64);
    val += __shfl_xor(val, 8, 64);
    const float tmp = th * (val + (float)DD * db[t]);
    if ((tid & 15) == 0) sm[t & 1][h] = tmp;
    __syncthreads();
    float m = -1e30f;
    #pragma unroll
    for (int hh = 0; hh < HH; ++hh) m = fmaxf(m, sm[t & 1][hh]);
    float ssum = 0.f;
    #pragma unroll
    for (int hh = 0; hh < HH; ++hh) ssum += __expf(sm[t & 1][hh] - m);
    const float pi = __expf(sm[t & 1][h] - m) * __builtin_amdgcn_rcpf(ssum);
    sp += pi;
    #pragma unroll
    for (int j = 0; j < 8; ++j) s2[j] += a2[j] * pi;
    if ((tid & 15) == 0) Pi[((size_t)b*TT + t0 + t) * HH + h] = pi;
    v = vn;
  }
  #pragma unroll
  for (int j = 0; j < 8; ++j) Srow[j] = s2[j];
  if ((tid & 15) == 0) SP[ch * (BB*HH) + b * HH + h] = sp;
}

// ---------------- Pass D: scan2_main -> ymid (bf16, (B,T,C)) ---------------
__global__ __launch_bounds__(256)
void pass_d(const u16* __restrict__ w, const float* __restrict__ S2,
            const float* __restrict__ SP, const float* __restrict__ Pi,
            u16* __restrict__ ymid)
{
  const int ch = blockIdx.x, b = blockIdx.y;
  const int tid = threadIdx.x;
  const int h = tid >> 4;
  const int t0 = ch * CHL;
  const u16* wrow = w + ((size_t)b*TT + t0) * CC + tid*8;
  u16* yrow = ymid + ((size_t)b*TT + t0) * CC + tid*8;
  const float* Srow = S2 + (size_t)ch * (BB*CC) + b * CC + tid*8;
  float c2[8];
  #pragma unroll
  for (int j = 0; j < 8; ++j) c2[j] = Srow[j];
  float cp = SP[ch * (BB*HH) + b * HH + h];
  const float* prow = Pi + ((size_t)b*TT + t0) * HH + h;
  uint4 v = *(const uint4*)wrow;
  for (int t = 0; t < CHL; ++t) {
    uint4 vn = v;
    if (t + 1 < CHL) vn = *(const uint4*)(wrow + (size_t)(t+1) * CC);
    const float pi = prow[(size_t)t * HH];
    cp += pi;
    const float invp = __builtin_amdgcn_rcpf(cp + 1e-8f);
    float a[8]; unpack8(v, a);
    float y[8];
    #pragma unroll
    for (int j = 0; j < 8; ++j) {
      const float a2 = a[j]*a[j];
      c2[j] += a2 * pi;
      const float d = c2[j] * invp;
      y[j] = -(a[j] * pi) * __builtin_amdgcn_rcpf(1.f + d);
    }
    uint4 o;
    o.x = (u32)f2bf(y[0]) | ((u32)f2bf(y[1]) << 16);
    o.y = (u32)f2bf(y[2]) | ((u32)f2bf(y[3]) << 16);
    o.z = (u32)f2bf(y[4]) | ((u32)f2bf(y[5]) << 16);
    o.w = (u32)f2bf(y[6]) | ((u32)f2bf(y[7]) << 16);
    *(uint4*)(yrow + (size_t)t * CC) = o;
    v = vn;
  }
}

// ---------------- launch ----------------------------------------------------
extern "C" void kernel_launch(void* const* d_in, const int* in_sizes, int n_in,
                              void* d_out, int out_size, void* d_ws, size_t ws_size,
                              hipStream_t stream) {
  const float* x     = (const float*)d_in[0];
  const float* Wa    = (const float*)d_in[1];
  const float* Wp    = (const float*)d_in[2];
  const float* temp  = (const float*)d_in[3];
  const float* dbias = (const float*)d_in[4];
  float* out = (float*)d_out;

  char* ws = (char*)d_ws;
  u16*  xb   = (u16*)(ws);                      // 67,108,864 B
  u16*  Wab  = (u16*)(ws + 67108864);           //  8,388,608 (dead after GEMM1)
  u16*  Wpb  = (u16*)(ws + 75497472);           //  8,388,608
  u16*  wbuf = (u16*)(ws + 83886080);           // 67,108,864 -> ends 150,994,944
  float* S1  = (float*)(ws + 150994944);        //  4,194,304 (S2 reuses in-place)
  float* SP  = (float*)(ws + 155189248);        //     32,768 -> ends 155,222,016
  float* Pi  = (float*)(ws + 67108864);         //  1,048,576 (overlays dead Wab)
  u16*  ymid = xb;                              // xb dead after GEMM1

  // 1) convert inputs to bf16
  cvt_f32_bf16<<<(MM*(long)KK)/8/256, 256, 0, stream>>>(x,  xb,  (long)MM*KK);
  cvt_f32_bf16<<<((long)CC*CC)/8/256, 256, 0, stream>>>(Wa, Wab, (long)CC*CC);
  cvt_f32_bf16<<<((long)CC*CC)/8/256, 256, 0, stream>>>(Wp, Wpb, (long)CC*CC);

  // 2) w = x @ Wa^T (bf16) + fused scan1 chunk partial sums -> S1
  dim3 gg(NNx/256, MM/256);
  gemm256<0,1><<<gg, 512, 0, stream>>>(xb, Wab, nullptr, wbuf, S1);

  // 3) scan1 offsets
  excl_big<<<(BB*CC)/256, 256, 0, stream>>>(S1);

  // 4) fused scan1_main + softmax + scan2_partial (writes Pi, S2=S1, SP)
  dim3 gc(NCH, BB);
  pass_c<<<gc, 256, 0, stream>>>(wbuf, S1, SP, Pi, temp, dbias);

  // 5) scan2 offsets
  excl_big<<<(BB*CC)/256, 256, 0, stream>>>(S1);
  excl_sp<<<1, 64, 0, stream>>>(SP);

  // 6) scan2 main -> ymid
  pass_d<<<gc, 256, 0, stream>>>(wbuf, S1, SP, Pi, ymid);

  // 7) out = y_mid @ Wp^T (f32 out)
  gemm256<1,0><<<gg, 512, 0, stream>>>(ymid, Wpb, out, nullptr, nullptr);
}

// Round 4
// 384.476 us; speedup vs baseline: 1.7093x; 1.0995x over previous
//
#include <hip/hip_runtime.h>
#include <hip/hip_bf16.h>
#include <stdint.h>

// Problem constants (fixed by setup_inputs)
#define BB 4
#define TT 4096
#define CC 2048
#define HH 16
#define DD 128
#define MM (BB*TT)   // 16384
#define KK CC        // 2048
#define NNx CC       // 2048
#define NTP 16       // K / 128 (tile-pairs of 2x64)

#define NCH 128
#define CHL (TT/NCH) // 32

typedef unsigned short u16;
typedef unsigned int   u32;
typedef __bf16 bf16x8 __attribute__((ext_vector_type(8)));
typedef float  f32x4  __attribute__((ext_vector_type(4)));

__device__ __forceinline__ float bf2f(u32 lo) {
  union { u32 u; float f; } z; z.u = lo << 16; return z.f;
}
__device__ __forceinline__ u16 f2bf(float f) {
  union { float f; u32 u; } z; z.f = f;
  u32 u = z.u;
  return (u16)((u + 0x7FFFu + ((u >> 16) & 1u)) >> 16); // RNE
}
__device__ __forceinline__ void unpack8(uint4 v, float* a) {
  a[0]=bf2f(v.x&0xffffu); a[1]=bf2f(v.x>>16);
  a[2]=bf2f(v.y&0xffffu); a[3]=bf2f(v.y>>16);
  a[4]=bf2f(v.z&0xffffu); a[5]=bf2f(v.z>>16);
  a[6]=bf2f(v.w&0xffffu); a[7]=bf2f(v.w>>16);
}

// ---------------- f32 -> bf16 convert (vectorized, 8 elem/thread) ----------
__global__ void cvt_f32_bf16(const float* __restrict__ in, u16* __restrict__ out, long n) {
  long i = ((long)blockIdx.x * blockDim.x + threadIdx.x) * 8;
  if (i >= n) return;
  float4 v0 = *(const float4*)(in + i);
  float4 v1 = *(const float4*)(in + i + 4);
  uint4 o;
  o.x = (u32)f2bf(v0.x) | ((u32)f2bf(v0.y) << 16);
  o.y = (u32)f2bf(v0.z) | ((u32)f2bf(v0.w) << 16);
  o.z = (u32)f2bf(v1.x) | ((u32)f2bf(v1.y) << 16);
  o.w = (u32)f2bf(v1.z) | ((u32)f2bf(v1.w) << 16);
  *(uint4*)(out + i) = o;
}

__device__ __forceinline__ void gload16(const void* g, void* l) {
  __builtin_amdgcn_global_load_lds(
      (__attribute__((address_space(1))) void*)g,
      (__attribute__((address_space(3))) void*)l, 16, 0, 0);
}

// ---------------- GEMM: C = A(M,K) * B(N,K)^T, 256x256 tile, 8-phase -------
// Proven structure (r2/r3): swizzled LDS 4-slot ring, counted vmcnt(4) at
// P4/P8, setprio around MFMA. NEW (r4): bijective XCD-chunked block remap
// (m204): XCD x owns m-stripe [8x,8x+8) x all n -> A panels L2-resident
// per-XCD, B streams from L3 with 4-way temporal reuse.
// EPI=1: fused scan1 chunk partial sums (per-32-row column sums of bf16^2).
template<int OUTF32, int EPI>
__global__ __launch_bounds__(512, 2)
void gemm256(const u16* __restrict__ A, const u16* __restrict__ Bm,
             float* __restrict__ Cf, u16* __restrict__ Cb,
             float* __restrict__ S1)
{
  __shared__ u16 As[4][8192];   // 4 x 16KB
  __shared__ u16 Bs[4][8192];   // 4 x 16KB   (total 128 KB)
  const int tid  = threadIdx.x;
  const int wid  = tid >> 6;
  const int lane = tid & 63;
  const int wm = wid >> 2, wn = wid & 3;     // 2 x 4 wave grid
  const int fr = lane & 15, kg = lane >> 4;
  // XCD-chunked bijective remap (nwg=512, 8 XCDs, XCD = orig%8)
  const int orig = blockIdx.x;
  const int nid  = ((orig & 7) << 6) | (orig >> 3);
  const int m0 = (nid >> 3) * 256;
  const int n0 = (nid & 7) * 256;

  const int srow = tid >> 2;                       // 0..127 (j adds 128)
  const int sc   = (tid & 3) ^ ((srow >> 1) & 3);  // pre-swizzled source chunk
  const u16* gA0 = A  + (size_t)(m0 + srow) * KK + sc * 8;
  const u16* gA1 = gA0 + (size_t)128 * KK;
  const u16* gB0 = Bm + (size_t)(n0 + srow) * KK + sc * 8;
  const u16* gB1 = gB0 + (size_t)128 * KK;
  const int ldst0 = wid * 512;
  const int ldst1 = 4096 + wid * 512;

  const int cs    = kg ^ ((fr >> 1) & 3);
  const int abase = (wm * 128 + fr) * 32 + cs * 8;
  const int bbase = (wn * 64  + fr) * 32 + cs * 8;

  f32x4 acc[8][4];
  #pragma unroll
  for (int i = 0; i < 8; ++i)
    #pragma unroll
    for (int j = 0; j < 4; ++j) acc[i][j] = (f32x4){0.f,0.f,0.f,0.f};

  auto stA = [&](int slot, int ko) {
    gload16(gA0 + ko, &As[slot][ldst0]);
    gload16(gA1 + ko, &As[slot][ldst1]);
  };
  auto stB = [&](int slot, int ko) {
    gload16(gB0 + ko, &Bs[slot][ldst0]);
    gload16(gB1 + ko, &Bs[slot][ldst1]);
  };

  stA(0, 0);  stB(0, 0);
  stA(1, 32); stB(1, 32);
  stA(2, 64); stB(2, 64);
  asm volatile("s_waitcnt vmcnt(2)" ::: "memory");
  __builtin_amdgcn_s_barrier();

  bf16x8 av[4], bv[4];

#define PH(CSLOT, MH, LOADB, STMT, DOWAIT) do {                               \
    _Pragma("unroll")                                                         \
    for (int f = 0; f < 4; ++f)                                               \
      av[f] = *(const bf16x8*)&As[CSLOT][abase + ((MH)*64 + f*16)*32];        \
    if (LOADB) {                                                              \
      _Pragma("unroll")                                                       \
      for (int f = 0; f < 4; ++f)                                             \
        bv[f] = *(const bf16x8*)&Bs[CSLOT][bbase + f*16*32];                  \
    }                                                                         \
    STMT;                                                                     \
    if (DOWAIT) asm volatile("s_waitcnt vmcnt(4)" ::: "memory");              \
    __builtin_amdgcn_s_barrier();                                             \
    __builtin_amdgcn_s_setprio(1);                                            \
    _Pragma("unroll")                                                         \
    for (int f = 0; f < 4; ++f)                                               \
      _Pragma("unroll")                                                       \
      for (int n = 0; n < 4; ++n)                                             \
        acc[(MH)*4+f][n] = __builtin_amdgcn_mfma_f32_16x16x32_bf16(          \
            av[f], bv[n], acc[(MH)*4+f][n], 0, 0, 0);                         \
    __builtin_amdgcn_s_setprio(0);                                            \
    __builtin_amdgcn_s_barrier();                                             \
  } while (0)

  for (int it = 0; it < NTP; ++it) {
    const int kb = it * 128;
    const bool nx = (it + 1 < NTP);
    PH(0, 0, 1, stA(3, kb + 96), 0);
    PH(0, 1, 0, stB(3, kb + 96), 0);
    PH(1, 0, 1, if (nx) stA(0, kb + 128), 0);
    PH(1, 1, 0, if (nx) stB(0, kb + 128), 1);
    PH(2, 0, 1, if (nx) stA(1, kb + 160), 0);
    PH(2, 1, 0, if (nx) stB(1, kb + 160), 0);
    PH(3, 0, 1, if (nx) stA(2, kb + 192), 0);
    PH(3, 1, 0, if (nx) stB(2, kb + 192), 1);
  }
#undef PH

  // C/D layout: col = lane&15, row = (lane>>4)*4 + reg   [m89/m91]
  const int row0 = m0 + wm * 128 + kg * 4;
  const int col0 = n0 + wn * 64 + fr;
  if (OUTF32) {
    #pragma unroll
    for (int mf = 0; mf < 8; ++mf)
      #pragma unroll
      for (int nf = 0; nf < 4; ++nf)
        #pragma unroll
        for (int r = 0; r < 4; ++r)
          Cf[(size_t)(row0 + mf*16 + r) * NNx + col0 + nf*16] = acc[mf][nf][r];
  } else {
    float csum[4][4];
    #pragma unroll
    for (int p = 0; p < 4; ++p)
      #pragma unroll
      for (int nf = 0; nf < 4; ++nf) csum[p][nf] = 0.f;
    #pragma unroll
    for (int mf = 0; mf < 8; ++mf)
      #pragma unroll
      for (int nf = 0; nf < 4; ++nf)
        #pragma unroll
        for (int r = 0; r < 4; ++r) {
          u16 hb = f2bf(acc[mf][nf][r]);
          Cb[(size_t)(row0 + mf*16 + r) * NNx + col0 + nf*16] = hb;
          if (EPI) { float av_ = bf2f(hb); csum[mf>>1][nf] += av_ * av_; }
        }
    if (EPI) {
      // reduce over kg (rows kg*4+r) and store per 32-row chunk
      const int b   = m0 >> 12;                 // m0 / TT
      const int ch0 = ((m0 & (TT-1)) >> 5) + wm * 4;
      #pragma unroll
      for (int p = 0; p < 4; ++p)
        #pragma unroll
        for (int nf = 0; nf < 4; ++nf) {
          float v = csum[p][nf];
          v += __shfl_xor(v, 16, 64);
          v += __shfl_xor(v, 32, 64);
          if (kg == 0)
            S1[(size_t)(ch0 + p) * (BB*CC) + b * CC + col0 + nf*16] = v;
        }
    }
  }
}

// ---------------- exclusive scan over chunk axis ---------------------------
// S layout: [NCH][BB*CC]; one thread per (b,c) column, coalesced.
__global__ void excl_big(float* __restrict__ p) {
  const int g = blockIdx.x * 256 + threadIdx.x;   // 0..8191
  float run = 0.f;
  for (int ch = 0; ch < NCH; ++ch) {
    float v = p[(size_t)ch * (BB*CC) + g];
    p[(size_t)ch * (BB*CC) + g] = run;
    run += v;
  }
}
__global__ void excl_sp(float* __restrict__ p) {
  const int g = threadIdx.x;                       // 0..63 (b*HH+h)
  float run = 0.f;
  for (int ch = 0; ch < NCH; ++ch) {
    float v = p[ch * (BB*HH) + g];
    p[ch * (BB*HH) + g] = run;
    run += v;
  }
}

// ---------------- Pass C: scan1_main + head softmax + scan2_partial --------
// block = (chunk, b); 256 threads cover all 2048 channels (8 per thread).
__global__ __launch_bounds__(256)
void pass_c(const u16* __restrict__ w, float* __restrict__ S,
            float* __restrict__ SP, float* __restrict__ Pi,
            const float* __restrict__ temp, const float* __restrict__ dbias)
{
  __shared__ float sm[2][HH];
  const int ch = blockIdx.x, b = blockIdx.y;
  const int tid = threadIdx.x;
  const int h = tid >> 4;
  const int t0 = ch * CHL;
  const u16* wrow = w + ((size_t)b*TT + t0) * CC + tid*8;
  float* Srow = S + (size_t)ch * (BB*CC) + b * CC + tid*8;
  float c0[8], s2[8];
  #pragma unroll
  for (int j = 0; j < 8; ++j) { c0[j] = Srow[j]; s2[j] = 0.f; }
  const float th = temp[h];
  const float* db = dbias + (size_t)h * TT + t0;
  float sp = 0.f;
  uint4 v = *(const uint4*)wrow;
  for (int t = 0; t < CHL; ++t) {
    uint4 vn = v;
    if (t + 1 < CHL) vn = *(const uint4*)(wrow + (size_t)(t+1) * CC);
    float a2[8];
    { float a[8]; unpack8(v, a);
      #pragma unroll
      for (int j = 0; j < 8; ++j) a2[j] = a[j]*a[j]; }
    float val = 0.f;
    #pragma unroll
    for (int j = 0; j < 8; ++j) {
      c0[j] += a2[j];
      val += a2[j] * __builtin_amdgcn_rcpf(fmaxf(c0[j], 1e-12f));
    }
    val += __shfl_xor(val, 1, 64);
    val += __shfl_xor(val, 2, 64);
    val += __shfl_xor(val, 4, 64);
    val += __shfl_xor(val, 8, 64);
    const float tmp = th * (val + (float)DD * db[t]);
    if ((tid & 15) == 0) sm[t & 1][h] = tmp;
    __syncthreads();
    float m = -1e30f;
    #pragma unroll
    for (int hh = 0; hh < HH; ++hh) m = fmaxf(m, sm[t & 1][hh]);
    float ssum = 0.f;
    #pragma unroll
    for (int hh = 0; hh < HH; ++hh) ssum += __expf(sm[t & 1][hh] - m);
    const float pi = __expf(sm[t & 1][h] - m) * __builtin_amdgcn_rcpf(ssum);
    sp += pi;
    #pragma unroll
    for (int j = 0; j < 8; ++j) s2[j] += a2[j] * pi;
    if ((tid & 15) == 0) Pi[((size_t)b*TT + t0 + t) * HH + h] = pi;
    v = vn;
  }
  #pragma unroll
  for (int j = 0; j < 8; ++j) Srow[j] = s2[j];
  if ((tid & 15) == 0) SP[ch * (BB*HH) + b * HH + h] = sp;
}

// ---------------- Pass D: scan2_main -> ymid (bf16, (B,T,C)) ---------------
__global__ __launch_bounds__(256)
void pass_d(const u16* __restrict__ w, const float* __restrict__ S2,
            const float* __restrict__ SP, const float* __restrict__ Pi,
            u16* __restrict__ ymid)
{
  const int ch = blockIdx.x, b = blockIdx.y;
  const int tid = threadIdx.x;
  const int h = tid >> 4;
  const int t0 = ch * CHL;
  const u16* wrow = w + ((size_t)b*TT + t0) * CC + tid*8;
  u16* yrow = ymid + ((size_t)b*TT + t0) * CC + tid*8;
  const float* Srow = S2 + (size_t)ch * (BB*CC) + b * CC + tid*8;
  float c2[8];
  #pragma unroll
  for (int j = 0; j < 8; ++j) c2[j] = Srow[j];
  float cp = SP[ch * (BB*HH) + b * HH + h];
  const float* prow = Pi + ((size_t)b*TT + t0) * HH + h;
  uint4 v = *(const uint4*)wrow;
  for (int t = 0; t < CHL; ++t) {
    uint4 vn = v;
    if (t + 1 < CHL) vn = *(const uint4*)(wrow + (size_t)(t+1) * CC);
    const float pi = prow[(size_t)t * HH];
    cp += pi;
    const float invp = __builtin_amdgcn_rcpf(cp + 1e-8f);
    float a[8]; unpack8(v, a);
    float y[8];
    #pragma unroll
    for (int j = 0; j < 8; ++j) {
      const float a2 = a[j]*a[j];
      c2[j] += a2 * pi;
      const float d = c2[j] * invp;
      y[j] = -(a[j] * pi) * __builtin_amdgcn_rcpf(1.f + d);
    }
    uint4 o;
    o.x = (u32)f2bf(y[0]) | ((u32)f2bf(y[1]) << 16);
    o.y = (u32)f2bf(y[2]) | ((u32)f2bf(y[3]) << 16);
    o.z = (u32)f2bf(y[4]) | ((u32)f2bf(y[5]) << 16);
    o.w = (u32)f2bf(y[6]) | ((u32)f2bf(y[7]) << 16);
    *(uint4*)(yrow + (size_t)t * CC) = o;
    v = vn;
  }
}

// ---------------- launch ----------------------------------------------------
extern "C" void kernel_launch(void* const* d_in, const int* in_sizes, int n_in,
                              void* d_out, int out_size, void* d_ws, size_t ws_size,
                              hipStream_t stream) {
  const float* x     = (const float*)d_in[0];
  const float* Wa    = (const float*)d_in[1];
  const float* Wp    = (const float*)d_in[2];
  const float* temp  = (const float*)d_in[3];
  const float* dbias = (const float*)d_in[4];
  float* out = (float*)d_out;

  char* ws = (char*)d_ws;
  u16*  xb   = (u16*)(ws);                      // 67,108,864 B
  u16*  Wab  = (u16*)(ws + 67108864);           //  8,388,608 (dead after GEMM1)
  u16*  Wpb  = (u16*)(ws + 75497472);           //  8,388,608
  u16*  wbuf = (u16*)(ws + 83886080);           // 67,108,864 -> ends 150,994,944
  float* S1  = (float*)(ws + 150994944);        //  4,194,304 (S2 reuses in-place)
  float* SP  = (float*)(ws + 155189248);        //     32,768 -> ends 155,222,016
  float* Pi  = (float*)(ws + 67108864);         //  1,048,576 (overlays dead Wab)
  u16*  ymid = xb;                              // xb dead after GEMM1

  // 1) convert inputs to bf16
  cvt_f32_bf16<<<(MM*(long)KK)/8/256, 256, 0, stream>>>(x,  xb,  (long)MM*KK);
  cvt_f32_bf16<<<((long)CC*CC)/8/256, 256, 0, stream>>>(Wa, Wab, (long)CC*CC);
  cvt_f32_bf16<<<((long)CC*CC)/8/256, 256, 0, stream>>>(Wp, Wpb, (long)CC*CC);

  // 2) w = x @ Wa^T (bf16) + fused scan1 chunk partial sums -> S1
  gemm256<0,1><<<512, 512, 0, stream>>>(xb, Wab, nullptr, wbuf, S1);

  // 3) scan1 offsets
  excl_big<<<(BB*CC)/256, 256, 0, stream>>>(S1);

  // 4) fused scan1_main + softmax + scan2_partial (writes Pi, S2=S1, SP)
  dim3 gc(NCH, BB);
  pass_c<<<gc, 256, 0, stream>>>(wbuf, S1, SP, Pi, temp, dbias);

  // 5) scan2 offsets
  excl_big<<<(BB*CC)/256, 256, 0, stream>>>(S1);
  excl_sp<<<1, 64, 0, stream>>>(SP);

  // 6) scan2 main -> ymid
  pass_d<<<gc, 256, 0, stream>>>(wbuf, S1, SP, Pi, ymid);

  // 7) out = y_mid @ Wp^T (f32 out)
  gemm256<1,0><<<512, 512, 0, stream>>>(ymid, Wpb, out, nullptr, nullptr);
}